// Round 9
// baseline (2604.342 us; speedup 1.0000x reference)
//
#include <hip/hip_runtime.h>
#include <math.h>

typedef __attribute__((ext_vector_type(8))) __bf16 bf16x8;
typedef __attribute__((ext_vector_type(4))) __bf16 bf16x4;
typedef __attribute__((ext_vector_type(2))) __bf16 bf16x2;
typedef __attribute__((ext_vector_type(4))) float f32x4;

#define MFMA_BF16 __builtin_amdgcn_mfma_f32_16x16x32_bf16

constexpr int LAY = 6, E = 768, HH = 4, DH = 192, FF = 3072, BB = 8, SS = 1024, MM = 8192;
constexpr float ATT_SCALE = 0.03608439182435161f;   // 768^-0.5 (source scales by E^-0.5)

__device__ __forceinline__ void gl2lds16(const void* g, void* l) {
    __builtin_amdgcn_global_load_lds(
        (const __attribute__((address_space(1))) void*)g,
        (__attribute__((address_space(3))) void*)l, 16, 0, 0);
}

// fast GELU (tanh form): max abs err ~3e-4, well under bf16 noise
__device__ __forceinline__ float gelu_fast(float v) {
    float y2 = 1.5957691216057308f * v * (1.0f + 0.044715f * v * v);  // 2*0.79788456*(v+0.044715v^3)
    return v * (1.0f - 1.0f / (__expf(y2) + 1.0f));
}

// ---------------- weight cast fp32 -> bf16 (6 tensors of one layer) ----------------
struct Cast6 {
    const float* src[6];
    __bf16* dst[6];
    int cum4[7];   // cumulative float4 counts
};

__global__ __launch_bounds__(256) void cast6_kernel(Cast6 c, int total4) {
    int stride = gridDim.x * 256;
    for (int i = blockIdx.x * 256 + threadIdx.x; i < total4; i += stride) {
        int rgn = 0;
#pragma unroll
        for (int k = 1; k < 6; ++k) rgn += (i >= c.cum4[k]) ? 1 : 0;
        int off = i - c.cum4[rgn];
        f32x4 v = ((const f32x4*)c.src[rgn])[off];
        bf16x4 o;
        o[0] = (__bf16)v[0]; o[1] = (__bf16)v[1]; o[2] = (__bf16)v[2]; o[3] = (__bf16)v[3];
        ((bf16x4*)c.dst[rgn])[off] = o;
    }
}

// ---------------- layernorm: fp32 x -> bf16 h ----------------
__global__ __launch_bounds__(256) void ln_kernel(const float* __restrict__ x,
                                                 const float* __restrict__ gamma,
                                                 const float* __restrict__ beta,
                                                 __bf16* __restrict__ out) {
    size_t row = blockIdx.x;
    const float* xr = x + row * E;
    int t = threadIdx.x;
    float v0 = xr[t], v1 = xr[t + 256], v2 = xr[t + 512];
    float s = v0 + v1 + v2;
    float q = v0 * v0 + v1 * v1 + v2 * v2;
#pragma unroll
    for (int m = 1; m < 64; m <<= 1) { s += __shfl_xor(s, m); q += __shfl_xor(q, m); }
    __shared__ float red[8];
    int w = t >> 6;
    if ((t & 63) == 0) { red[w] = s; red[4 + w] = q; }
    __syncthreads();
    s = red[0] + red[1] + red[2] + red[3];
    q = red[4] + red[5] + red[6] + red[7];
    float mu = s * (1.0f / E);
    float var = q * (1.0f / E) - mu * mu;
    float rs = rsqrtf(var + 1e-5f);
    __bf16* orow = out + row * E;
    orow[t]       = (__bf16)((v0 - mu) * rs * gamma[t]       + beta[t]);
    orow[t + 256] = (__bf16)((v1 - mu) * rs * gamma[t + 256] + beta[t + 256]);
    orow[t + 512] = (__bf16)((v2 - mu) * rs * gamma[t + 512] + beta[t + 512]);
}

// ---------------- GEMM 128x128, BK=32, 4 waves, double-buffered in-wave prefetch ----
// C[M,N] = A[M,K] @ W[N,K]^T. 2 x 16KB LDS bufs -> up to 5 blocks/CU. Loop:
// { stage(t+1) ; compute(t) ; __syncthreads }  — loads of t+1 hide under compute(t).
// No inline asm: compiler schedules waitcnts. T2 chunk-XOR swizzle (2-lane/bank),
// T1 XCD swizzle. EPI: 0 = store bf16 ; 1 = +bias,fastGELU,bf16 ; 2 = fp32 atomicAdd.
// SPLITK: blockIdx.z picks K-slice; bias added by slice 0 only.
template <int EPI, int SPLITK>
__global__ __launch_bounds__(256, 5) void gemm128(
    const __bf16* __restrict__ A,
    const __bf16* __restrict__ B0, const __bf16* __restrict__ B1, const __bf16* __restrict__ B2,
    void* __restrict__ O0, void* __restrict__ O1, void* __restrict__ O2,
    const float* __restrict__ bias, int M, int N, int K) {
    __shared__ __bf16 lds[2 * 8192];   // buf: [A 128x32 | B 128x32] = 16 KB each
    int z = blockIdx.z;
    const __bf16* Bw;
    void* Out;
    int ksp;
    if constexpr (SPLITK > 1) {
        Bw = B0; Out = O0; ksp = z;
    } else {
        Bw = (z == 0) ? B0 : (z == 1) ? B1 : B2;
        Out = (z == 0) ? O0 : (z == 1) ? O1 : O2;
        ksp = 0;
    }
    int Keff = K / SPLITK;
    int t = threadIdx.x;
    int w = t >> 6, lane = t & 63, b4 = lane >> 4, r = lane & 15;
    // T1: bijective XCD swizzle over (x,y); all launches have gx*gy % 8 == 0
    int gx = gridDim.x;
    int nwg = gx * gridDim.y;
    int bid = blockIdx.y * gx + blockIdx.x;
    int cpx = nwg >> 3;
    int swz = (bid & 7) * cpx + (bid >> 3);
    int bx = swz % gx, by = swz / gx;
    int mbase = by * 128, nbase = bx * 128;
    int wr = w >> 1, wc = w & 1;             // 2 (M) x 2 (N) waves, each owns 64x64
    const f32x4 fz = {0.f, 0.f, 0.f, 0.f};
    f32x4 acc[4][4];
#pragma unroll
    for (int a1 = 0; a1 < 4; ++a1)
#pragma unroll
        for (int a2 = 0; a2 < 4; ++a2) acc[a1][a2] = fz;
    const __bf16* Ap = A + (size_t)mbase * K + ksp * Keff;
    const __bf16* Bp = Bw + (size_t)nbase * K + ksp * Keff;
    int nk = Keff >> 5;

    // per-thread staging pointers: 2 chunks per matrix per tile.
    // chunk c = i*256+t -> row = c>>2, src col = ((c ^ row ^ (row>>2)) & 3)*8
    const __bf16* sA[2];
    const __bf16* sB[2];
#pragma unroll
    for (int i = 0; i < 2; ++i) {
        int c = i * 256 + t;
        int row = c >> 2;
        int col = ((c ^ row ^ (row >> 2)) & 3) * 8;
        sA[i] = Ap + (size_t)row * K + col;
        sB[i] = Bp + (size_t)row * K + col;
    }

    // read-side swizzle: chunk = b4 ^ (r&3) ^ ((r>>2)&3)
    int chnk = (b4 ^ (r & 3) ^ ((r >> 2) & 3)) * 8;
    int arow = (wr * 64 + r) * 32 + chnk;           // + mi*512
    int brow = 4096 + (wc * 64 + r) * 32 + chnk;    // + ni*512

    auto stage = [&](int bufsel) {
        __bf16* dst = lds + bufsel * 8192;
#pragma unroll
        for (int i = 0; i < 2; ++i) {
            gl2lds16(sA[i], (void*)(dst + i * 2048 + w * 512));
            gl2lds16(sB[i], (void*)(dst + 4096 + i * 2048 + w * 512));
            sA[i] += 32; sB[i] += 32;
        }
    };

    stage(0);
    __syncthreads();
    for (int kt = 0; kt < nk; ++kt) {
        if (kt + 1 < nk) stage((kt + 1) & 1);
        const __bf16* sa = lds + (kt & 1) * 8192;
        bf16x8 af[4], bfr[4];
#pragma unroll
        for (int mi = 0; mi < 4; ++mi)
            af[mi] = *(const bf16x8*)(sa + arow + mi * 512);
#pragma unroll
        for (int ni = 0; ni < 4; ++ni)
            bfr[ni] = *(const bf16x8*)(sa + brow + ni * 512);
#pragma unroll
        for (int mi = 0; mi < 4; ++mi)
#pragma unroll
            for (int ni = 0; ni < 4; ++ni)
                acc[mi][ni] = MFMA_BF16(af[mi], bfr[ni], acc[mi][ni], 0, 0, 0);
        __syncthreads();
    }

    // epilogue: C row = b4*4 + j, col = r (per 16x16 tile)
#pragma unroll
    for (int mi = 0; mi < 4; ++mi) {
#pragma unroll
        for (int ni = 0; ni < 4; ++ni) {
            int col = nbase + wc * 64 + ni * 16 + r;
#pragma unroll
            for (int j = 0; j < 4; ++j) {
                int rowi = mbase + wr * 64 + mi * 16 + b4 * 4 + j;
                float v = acc[mi][ni][j];
                if constexpr (EPI == 0) {
                    ((__bf16*)Out)[(size_t)rowi * N + col] = (__bf16)v;
                } else if constexpr (EPI == 1) {
                    v += bias[col];
                    ((__bf16*)Out)[(size_t)rowi * N + col] = (__bf16)gelu_fast(v);
                } else {
                    float* X = (float*)Out;
                    float add = v + (ksp == 0 ? bias[col] : 0.0f);
                    atomicAdd(&X[(size_t)rowi * N + col], add);
                }
            }
        }
    }
}

// ---------------- V transpose: head-flat (S,D) -> Vt[bh*D + d][s] ----------------
__global__ __launch_bounds__(256) void vtrans_kernel(const __bf16* __restrict__ v,
                                                     __bf16* __restrict__ vt) {
    __shared__ __bf16 tile[64 * 72];   // [s_local][d_local] padded
    int bh = blockIdx.y;
    int si = blockIdx.x / 3, di = blockIdx.x % 3;
    int t = threadIdx.x;
    const __bf16* src = v + (size_t)bh * (SS * DH) + (size_t)(si * 64) * DH + di * 64;
#pragma unroll
    for (int i = 0; i < 2; ++i) {
        int c = i * 256 + t;           // 0..511 chunks of 8
        int sl = c >> 3, dc = c & 7;
        *(bf16x8*)(tile + sl * 72 + dc * 8) = *(const bf16x8*)(src + (size_t)sl * DH + dc * 8);
    }
    __syncthreads();
    __bf16* dst = vt + ((size_t)bh * DH + di * 64) * SS + si * 64;
#pragma unroll
    for (int i = 0; i < 2; ++i) {
        int c = i * 256 + t;
        int dl = c >> 3, sc = c & 7;
        bf16x8 o;
#pragma unroll
        for (int e = 0; e < 8; ++e) o[e] = tile[(sc * 8 + e) * 72 + dl];
        *(bf16x8*)(dst + (size_t)dl * SS + sc * 8) = o;
    }
}

// ---------------- flash attention, one (b,h) head = contiguous (1024,192) ----------
__global__ __launch_bounds__(256) void attn_kernel(const __bf16* __restrict__ qp,
                                                   const __bf16* __restrict__ kp,
                                                   const __bf16* __restrict__ vtp,
                                                   __bf16* __restrict__ ao) {
    __shared__ __bf16 smK[64 * 192];     // [key][d], 16B-chunk XOR-swizzled
    __shared__ __bf16 smVt[192 * 64];    // [d][key], 16B-chunk XOR-swizzled
    __shared__ __bf16 smP[4 * 16 * 72];  // per-wave P tiles, padded
    int qt = blockIdx.x, h = blockIdx.y, b = blockIdx.z;
    int t = threadIdx.x, w = t >> 6, lane = t & 63, b4 = lane >> 4, r = lane & 15;
    size_t base = (size_t)b * (SS * E) + (size_t)h * (SS * DH);
    const __bf16* Q = qp + base;
    const __bf16* Kg = kp + base;
    const __bf16* VtG = vtp + (size_t)(b * HH + h) * DH * SS;   // rows d, length S
    int q0 = qt * 64 + w * 16;
    bf16x8 qf[6];
#pragma unroll
    for (int ks = 0; ks < 6; ++ks)
        qf[ks] = *(const bf16x8*)(Q + (size_t)(q0 + r) * DH + ks * 32 + b4 * 8);
    const f32x4 fz = {0.f, 0.f, 0.f, 0.f};
    f32x4 oacc[12];
#pragma unroll
    for (int i = 0; i < 12; ++i) oacc[i] = fz;
    float m_r[4], l_r[4];
#pragma unroll
    for (int j = 0; j < 4; ++j) { m_r[j] = -1e30f; l_r[j] = 0.f; }
    __bf16* smPw = smP + w * (16 * 72);

    for (int kt = 0; kt < 16; ++kt) {
        const __bf16* Ks = Kg + (size_t)kt * 64 * DH;
        // stage K: 64 rows x 24 chunks; LDS linear dest, source chunk low3 ^= row&7
#pragma unroll
        for (int i = 0; i < 6; ++i) {
            int c = i * 256 + t;                 // 0..1535
            int row = c / 24, cc = c - row * 24;
            int scc = (cc & 0x18) | ((cc ^ row) & 7);
            gl2lds16(Ks + (size_t)row * DH + scc * 8,
                     (void*)(smK + (i * 256 + w * 64) * 8));
        }
        // stage V^T: 192 rows x 8 chunks; rows stride S in global
#pragma unroll
        for (int i = 0; i < 6; ++i) {
            int c = i * 256 + t;                 // 0..1535
            int row = c >> 3, cc = c & 7;
            int scc = cc ^ (row & 7);
            gl2lds16(VtG + (size_t)row * SS + kt * 64 + scc * 8,
                     (void*)(smVt + (i * 256 + w * 64) * 8));
        }
        __syncthreads();
        // S = Q K^T * scale  (16 q  x 64 keys per wave)
        f32x4 sc[4];
#pragma unroll
        for (int nt = 0; nt < 4; ++nt) sc[nt] = fz;
#pragma unroll
        for (int ks = 0; ks < 6; ++ks) {
#pragma unroll
            for (int nt = 0; nt < 4; ++nt) {
                int cc = ks * 4 + b4;
                int ccs = (cc & 0x18) | ((cc ^ r) & 7);   // row&7 == r&7
                bf16x8 kf = *(const bf16x8*)(smK + (nt * 16 + r) * 192 + ccs * 8);
                sc[nt] = MFMA_BF16(qf[ks], kf, sc[nt], 0, 0, 0);
            }
        }
#pragma unroll
        for (int nt = 0; nt < 4; ++nt) sc[nt] *= ATT_SCALE;
        // online softmax
        float alpha[4];
#pragma unroll
        for (int j = 0; j < 4; ++j) {
            float mx = fmaxf(fmaxf(sc[0][j], sc[1][j]), fmaxf(sc[2][j], sc[3][j]));
#pragma unroll
            for (int msk = 1; msk < 16; msk <<= 1) mx = fmaxf(mx, __shfl_xor(mx, msk));
            float mn = fmaxf(m_r[j], mx);
            alpha[j] = __expf(m_r[j] - mn);
            m_r[j] = mn;
            float p0 = __expf(sc[0][j] - mn);
            float p1 = __expf(sc[1][j] - mn);
            float p2 = __expf(sc[2][j] - mn);
            float p3 = __expf(sc[3][j] - mn);
            sc[0][j] = p0; sc[1][j] = p1; sc[2][j] = p2; sc[3][j] = p3;
            float ps = p0 + p1 + p2 + p3;
#pragma unroll
            for (int msk = 1; msk < 16; msk <<= 1) ps += __shfl_xor(ps, msk);
            l_r[j] = l_r[j] * alpha[j] + ps;
        }
        {
            f32x4 a4 = {alpha[0], alpha[1], alpha[2], alpha[3]};
#pragma unroll
            for (int i = 0; i < 12; ++i) oacc[i] *= a4;
        }
        // P -> per-wave LDS (bf16)
#pragma unroll
        for (int nt = 0; nt < 4; ++nt)
#pragma unroll
            for (int j = 0; j < 4; ++j)
                smPw[(b4 * 4 + j) * 72 + nt * 16 + r] = (__bf16)sc[nt][j];
        __asm__ volatile("s_waitcnt lgkmcnt(0)" ::: "memory");
        // O += P V
#pragma unroll
        for (int kt2 = 0; kt2 < 2; ++kt2) {
            bf16x8 pa = *(const bf16x8*)(smPw + r * 72 + kt2 * 32 + b4 * 8);
#pragma unroll
            for (int nt = 0; nt < 12; ++nt) {
                int ccs = (kt2 * 4 + b4) ^ (r & 7);        // row&7 == r&7
                bf16x8 vf = *(const bf16x8*)(smVt + (nt * 16 + r) * 64 + ccs * 8);
                oacc[nt] = MFMA_BF16(pa, vf, oacc[nt], 0, 0, 0);
            }
        }
        __syncthreads();
    }
    // write O / l  -> ao[b, s, h*D + d]
    float inv[4];
#pragma unroll
    for (int j = 0; j < 4; ++j) inv[j] = 1.0f / l_r[j];
    __bf16* obase = ao + (size_t)b * (SS * E);
#pragma unroll
    for (int nt = 0; nt < 12; ++nt)
#pragma unroll
        for (int j = 0; j < 4; ++j) {
            int srow = q0 + b4 * 4 + j;
            obase[(size_t)srow * E + h * DH + nt * 16 + r] = (__bf16)(oacc[nt][j] * inv[j]);
        }
}

// ---------------------------------------------------------------------------------
extern "C" void kernel_launch(void* const* d_in, const int* in_sizes, int n_in,
                              void* d_out, int out_size, void* d_ws, size_t ws_size,
                              hipStream_t stream) {
    const float* hs   = (const float*)d_in[0];
    const float* ln1s = (const float*)d_in[1];
    const float* ln1b = (const float*)d_in[2];
    const float* wq   = (const float*)d_in[3];
    const float* wk   = (const float*)d_in[4];
    const float* wv   = (const float*)d_in[5];
    const float* wo   = (const float*)d_in[6];
    const float* bo   = (const float*)d_in[7];
    const float* ln2s = (const float*)d_in[8];
    const float* ln2b = (const float*)d_in[9];
    const float* w1   = (const float*)d_in[10];
    const float* b1   = (const float*)d_in[11];
    const float* w2   = (const float*)d_in[12];
    const float* b2   = (const float*)d_in[13];
    float* X = (float*)d_out;

    char* ws = (char*)d_ws;
    size_t off = 0;
    auto alloc = [&](size_t bytes) {
        char* p = ws + off;
        off += (bytes + 255) & ~(size_t)255;
        return p;
    };
    __bf16* wq_b = (__bf16*)alloc((size_t)E * E * 2);
    __bf16* wk_b = (__bf16*)alloc((size_t)E * E * 2);
    __bf16* wv_b = (__bf16*)alloc((size_t)E * E * 2);
    __bf16* wo_b = (__bf16*)alloc((size_t)E * E * 2);
    __bf16* w1_b = (__bf16*)alloc((size_t)FF * E * 2);
    __bf16* w2_b = (__bf16*)alloc((size_t)FF * E * 2);
    __bf16* h_b  = (__bf16*)alloc((size_t)MM * E * 2);
    // U = 4 slots of MM*E bf16 (50.3 MB), also aliased whole by FFN intermediate
    char* U = alloc((size_t)MM * FF * 2);
    const size_t SLOT = (size_t)MM * E * 2;
    __bf16* q_b  = (__bf16*)U;                  // slot 0
    __bf16* k_b  = (__bf16*)(U + SLOT);         // slot 1
    __bf16* v_b  = (__bf16*)(U + 2 * SLOT);     // slot 2 (dead after vtrans)
    __bf16* vt_b = (__bf16*)(U + 3 * SLOT);     // slot 3: [bh*D + d][s]
    __bf16* a_b  = (__bf16*)(U + 2 * SLOT);     // slot 2 reused for attn out
    __bf16* f_b  = (__bf16*)U;

    // x lives in d_out (fp32); fresh copy every call keeps graph replays idempotent
    hipMemcpyAsync(d_out, hs, (size_t)MM * E * 4, hipMemcpyDeviceToDevice, stream);

    for (int i = 0; i < LAY; ++i) {
        Cast6 c;
        c.src[0] = wq + (size_t)i * E * E;  c.dst[0] = wq_b;
        c.src[1] = wk + (size_t)i * E * E;  c.dst[1] = wk_b;
        c.src[2] = wv + (size_t)i * E * E;  c.dst[2] = wv_b;
        c.src[3] = wo + (size_t)i * E * E;  c.dst[3] = wo_b;
        c.src[4] = w1 + (size_t)i * FF * E; c.dst[4] = w1_b;
        c.src[5] = w2 + (size_t)i * FF * E; c.dst[5] = w2_b;
        int n4[6] = {E * E / 4, E * E / 4, E * E / 4, E * E / 4, FF * E / 4, FF * E / 4};
        c.cum4[0] = 0;
        for (int k = 0; k < 6; ++k) c.cum4[k + 1] = c.cum4[k] + n4[k];
        int total4 = c.cum4[6];
        cast6_kernel<<<1024, 256, 0, stream>>>(c, total4);

        ln_kernel<<<MM, 256, 0, stream>>>(X, ln1s + (size_t)i * E, ln1b + (size_t)i * E, h_b);

        gemm128<0, 1><<<dim3(E / 128, MM / 128, 3), 256, 0, stream>>>(
            h_b, wq_b, wk_b, wv_b, q_b, k_b, v_b, nullptr, MM, E, E);

        vtrans_kernel<<<dim3(48, 32), 256, 0, stream>>>(v_b, vt_b);

        attn_kernel<<<dim3(SS / 64, HH, BB), 256, 0, stream>>>(q_b, k_b, vt_b, a_b);

        gemm128<2, 3><<<dim3(E / 128, MM / 128, 3), 256, 0, stream>>>(
            a_b, wo_b, wo_b, wo_b, X, X, X, bo + (size_t)i * E, MM, E, E);

        ln_kernel<<<MM, 256, 0, stream>>>(X, ln2s + (size_t)i * E, ln2b + (size_t)i * E, h_b);

        gemm128<1, 1><<<dim3(FF / 128, MM / 128, 1), 256, 0, stream>>>(
            h_b, w1_b, w1_b, w1_b, f_b, f_b, f_b, b1 + (size_t)i * FF, MM, FF, E);

        gemm128<2, 3><<<dim3(E / 128, MM / 128, 3), 256, 0, stream>>>(
            f_b, w2_b, w2_b, w2_b, X, X, X, b2 + (size_t)i * E, MM, E, FF);
    }
}

// Round 10
// 1772.956 us; speedup vs baseline: 1.4689x; 1.4689x over previous
//
#include <hip/hip_runtime.h>
#include <math.h>

typedef __attribute__((ext_vector_type(8))) __bf16 bf16x8;
typedef __attribute__((ext_vector_type(4))) __bf16 bf16x4;
typedef __attribute__((ext_vector_type(2))) __bf16 bf16x2;
typedef __attribute__((ext_vector_type(4))) float f32x4;

#define MFMA_BF16 __builtin_amdgcn_mfma_f32_16x16x32_bf16

constexpr int LAY = 6, E = 768, HH = 4, DH = 192, FF = 3072, BB = 8, SS = 1024, MM = 8192;
constexpr float ATT_SCALE = 0.03608439182435161f;   // 768^-0.5 (source scales by E^-0.5)

__device__ __forceinline__ void gl2lds16(const void* g, void* l) {
    __builtin_amdgcn_global_load_lds(
        (const __attribute__((address_space(1))) void*)g,
        (__attribute__((address_space(3))) void*)l, 16, 0, 0);
}

// fast GELU (tanh form): max abs err ~3e-4, well under bf16 noise
__device__ __forceinline__ float gelu_fast(float v) {
    float y2 = 1.5957691216057308f * v * (1.0f + 0.044715f * v * v);
    return v * (1.0f - 1.0f / (__expf(y2) + 1.0f));
}

// ---------------- weight cast fp32 -> bf16 (6 tensors of one layer) ----------------
struct Cast6 {
    const float* src[6];
    __bf16* dst[6];
    int cum4[7];   // cumulative float4 counts
};

__global__ __launch_bounds__(256) void cast6_kernel(Cast6 c, int total4) {
    int stride = gridDim.x * 256;
    for (int i = blockIdx.x * 256 + threadIdx.x; i < total4; i += stride) {
        int rgn = 0;
#pragma unroll
        for (int k = 1; k < 6; ++k) rgn += (i >= c.cum4[k]) ? 1 : 0;
        int off = i - c.cum4[rgn];
        f32x4 v = ((const f32x4*)c.src[rgn])[off];
        bf16x4 o;
        o[0] = (__bf16)v[0]; o[1] = (__bf16)v[1]; o[2] = (__bf16)v[2]; o[3] = (__bf16)v[3];
        ((bf16x4*)c.dst[rgn])[off] = o;
    }
}

// ---------------- layernorm: fp32 x -> bf16 h ----------------
__global__ __launch_bounds__(256) void ln_kernel(const float* __restrict__ x,
                                                 const float* __restrict__ gamma,
                                                 const float* __restrict__ beta,
                                                 __bf16* __restrict__ out) {
    size_t row = blockIdx.x;
    const float* xr = x + row * E;
    int t = threadIdx.x;
    float v0 = xr[t], v1 = xr[t + 256], v2 = xr[t + 512];
    float s = v0 + v1 + v2;
    float q = v0 * v0 + v1 * v1 + v2 * v2;
#pragma unroll
    for (int m = 1; m < 64; m <<= 1) { s += __shfl_xor(s, m); q += __shfl_xor(q, m); }
    __shared__ float red[8];
    int w = t >> 6;
    if ((t & 63) == 0) { red[w] = s; red[4 + w] = q; }
    __syncthreads();
    s = red[0] + red[1] + red[2] + red[3];
    q = red[4] + red[5] + red[6] + red[7];
    float mu = s * (1.0f / E);
    float var = q * (1.0f / E) - mu * mu;
    float rs = rsqrtf(var + 1e-5f);
    __bf16* orow = out + row * E;
    orow[t]       = (__bf16)((v0 - mu) * rs * gamma[t]       + beta[t]);
    orow[t + 256] = (__bf16)((v1 - mu) * rs * gamma[t + 256] + beta[t + 256]);
    orow[t + 512] = (__bf16)((v2 - mu) * rs * gamma[t + 512] + beta[t + 512]);
}

// ---------------- GEMM 128x128, BK=64, 4 waves — m97-faithful + T5 setprio ---------
// C[M,N] = A[M,K] @ W[N,K]^T. Single 32KB LDS buffer, plain __syncthreads, compiler-
// scheduled waitcnts. T2 chunk-XOR swizzle (verified 0-conflict at BK=64), T1 XCD
// swizzle. EPI: 0 = store bf16 ; 1 = +bias,fastGELU,bf16 ; 2 = fp32 atomicAdd X.
// SPLITK=2: blockIdx.z picks K-half; bias added by split 0 only.
template <int EPI, int SPLITK>
__global__ __launch_bounds__(256, 4) void gemm128(
    const __bf16* __restrict__ A,
    const __bf16* __restrict__ B0, const __bf16* __restrict__ B1, const __bf16* __restrict__ B2,
    void* __restrict__ O0, void* __restrict__ O1, void* __restrict__ O2,
    const float* __restrict__ bias, int M, int N, int K) {
    __shared__ __bf16 lds[2 * 8192];   // A[128][64] | B[128][64] = 32 KiB
    int z = blockIdx.z;
    const __bf16* Bw;
    void* Out;
    int ksp;
    if constexpr (SPLITK > 1) {
        Bw = B0; Out = O0; ksp = z;
    } else {
        Bw = (z == 0) ? B0 : (z == 1) ? B1 : B2;
        Out = (z == 0) ? O0 : (z == 1) ? O1 : O2;
        ksp = 0;
    }
    int Keff = K / SPLITK;
    int t = threadIdx.x;
    int w = t >> 6, lane = t & 63, b4 = lane >> 4, r = lane & 15;
    // T1: bijective XCD swizzle over (x,y); all launches have gx*gy % 8 == 0
    int gx = gridDim.x;
    int nwg = gx * gridDim.y;
    int bid = blockIdx.y * gx + blockIdx.x;
    int cpx = nwg >> 3;
    int swz = (bid & 7) * cpx + (bid >> 3);
    int bx = swz % gx, by = swz / gx;
    int mbase = by * 128, nbase = bx * 128;
    int wr = w >> 1, wc = w & 1;             // 2 (M) x 2 (N) waves, each owns 64x64
    const f32x4 fz = {0.f, 0.f, 0.f, 0.f};
    f32x4 acc[4][4];
#pragma unroll
    for (int a1 = 0; a1 < 4; ++a1)
#pragma unroll
        for (int a2 = 0; a2 < 4; ++a2) acc[a1][a2] = fz;
    const __bf16* Ap = A + (size_t)mbase * K + ksp * Keff;
    const __bf16* Bp = Bw + (size_t)nbase * K + ksp * Keff;
    int nk = Keff >> 6;

    // per-thread staging pointers: 4 chunks per matrix per K-tile.
    // chunk c = i*256+t -> row = c>>3, src col = ((c^row)&7)*8 (chunk-XOR swizzle).
    const __bf16* sA[4];
    const __bf16* sB[4];
#pragma unroll
    for (int i = 0; i < 4; ++i) {
        int c = i * 256 + t;
        int row = c >> 3;
        int col = ((c ^ row) & 7) * 8;
        sA[i] = Ap + (size_t)row * K + col;
        sB[i] = Bp + (size_t)row * K + col;
    }

    // per-lane read bases (read-side swizzle: chunk = (ks*4+b4) ^ (r&7))
    int ch0 = ((b4) ^ (r & 7)) * 8;          // ks=0
    int ch1 = ((4 + b4) ^ (r & 7)) * 8;      // ks=1
    int arow = (wr * 64 + r) * 64;           // + mi*1024
    int brow = 8192 + (wc * 64 + r) * 64;    // + ni*1024

    for (int kt = 0; kt < nk; ++kt) {
#pragma unroll
        for (int i = 0; i < 4; ++i) {
            gl2lds16(sA[i], (void*)(lds + i * 2048 + w * 512));
            gl2lds16(sB[i], (void*)(lds + 8192 + i * 2048 + w * 512));
            sA[i] += 64; sB[i] += 64;
        }
        __syncthreads();
#pragma unroll
        for (int ks = 0; ks < 2; ++ks) {
            int chk = ks ? ch1 : ch0;
            bf16x8 af[4], bfr[4];
#pragma unroll
            for (int mi = 0; mi < 4; ++mi)
                af[mi] = *(const bf16x8*)(lds + arow + mi * 1024 + chk);
#pragma unroll
            for (int ni = 0; ni < 4; ++ni)
                bfr[ni] = *(const bf16x8*)(lds + brow + ni * 1024 + chk);
            __builtin_amdgcn_s_setprio(1);
#pragma unroll
            for (int mi = 0; mi < 4; ++mi)
#pragma unroll
                for (int ni = 0; ni < 4; ++ni)
                    acc[mi][ni] = MFMA_BF16(af[mi], bfr[ni], acc[mi][ni], 0, 0, 0);
            __builtin_amdgcn_s_setprio(0);
        }
        __syncthreads();
    }

    // epilogue: C row = b4*4 + j, col = r (per 16x16 tile)
#pragma unroll
    for (int mi = 0; mi < 4; ++mi) {
#pragma unroll
        for (int ni = 0; ni < 4; ++ni) {
            int col = nbase + wc * 64 + ni * 16 + r;
#pragma unroll
            for (int j = 0; j < 4; ++j) {
                int rowi = mbase + wr * 64 + mi * 16 + b4 * 4 + j;
                float v = acc[mi][ni][j];
                if constexpr (EPI == 0) {
                    ((__bf16*)Out)[(size_t)rowi * N + col] = (__bf16)v;
                } else if constexpr (EPI == 1) {
                    v += bias[col];
                    ((__bf16*)Out)[(size_t)rowi * N + col] = (__bf16)gelu_fast(v);
                } else {
                    float* X = (float*)Out;
                    float add = v + (ksp == 0 ? bias[col] : 0.0f);
                    atomicAdd(&X[(size_t)rowi * N + col], add);
                }
            }
        }
    }
}

// ---------------- V transpose: head-flat (S,D) -> Vt[bh*D + d][s] ----------------
__global__ __launch_bounds__(256) void vtrans_kernel(const __bf16* __restrict__ v,
                                                     __bf16* __restrict__ vt) {
    __shared__ __bf16 tile[64 * 72];   // [s_local][d_local] padded
    int bh = blockIdx.y;
    int si = blockIdx.x / 3, di = blockIdx.x % 3;
    int t = threadIdx.x;
    const __bf16* src = v + (size_t)bh * (SS * DH) + (size_t)(si * 64) * DH + di * 64;
#pragma unroll
    for (int i = 0; i < 2; ++i) {
        int c = i * 256 + t;           // 0..511 chunks of 8
        int sl = c >> 3, dc = c & 7;
        *(bf16x8*)(tile + sl * 72 + dc * 8) = *(const bf16x8*)(src + (size_t)sl * DH + dc * 8);
    }
    __syncthreads();
    __bf16* dst = vt + ((size_t)bh * DH + di * 64) * SS + si * 64;
#pragma unroll
    for (int i = 0; i < 2; ++i) {
        int c = i * 256 + t;
        int dl = c >> 3, sc = c & 7;
        bf16x8 o;
#pragma unroll
        for (int e = 0; e < 8; ++e) o[e] = tile[(sc * 8 + e) * 72 + dl];
        *(bf16x8*)(dst + (size_t)dl * SS + sc * 8) = o;
    }
}

// ---------------- flash attention, one (b,h) head = contiguous (1024,192) ----------
__global__ __launch_bounds__(256) void attn_kernel(const __bf16* __restrict__ qp,
                                                   const __bf16* __restrict__ kp,
                                                   const __bf16* __restrict__ vtp,
                                                   __bf16* __restrict__ ao) {
    __shared__ __bf16 smK[64 * 192];     // [key][d], 16B-chunk XOR-swizzled
    __shared__ __bf16 smVt[192 * 64];    // [d][key], 16B-chunk XOR-swizzled
    __shared__ __bf16 smP[4 * 16 * 72];  // per-wave P tiles, padded
    int qt = blockIdx.x, h = blockIdx.y, b = blockIdx.z;
    int t = threadIdx.x, w = t >> 6, lane = t & 63, b4 = lane >> 4, r = lane & 15;
    size_t base = (size_t)b * (SS * E) + (size_t)h * (SS * DH);
    const __bf16* Q = qp + base;
    const __bf16* Kg = kp + base;
    const __bf16* VtG = vtp + (size_t)(b * HH + h) * DH * SS;   // rows d, length S
    int q0 = qt * 64 + w * 16;
    bf16x8 qf[6];
#pragma unroll
    for (int ks = 0; ks < 6; ++ks)
        qf[ks] = *(const bf16x8*)(Q + (size_t)(q0 + r) * DH + ks * 32 + b4 * 8);
    const f32x4 fz = {0.f, 0.f, 0.f, 0.f};
    f32x4 oacc[12];
#pragma unroll
    for (int i = 0; i < 12; ++i) oacc[i] = fz;
    float m_r[4], l_r[4];
#pragma unroll
    for (int j = 0; j < 4; ++j) { m_r[j] = -1e30f; l_r[j] = 0.f; }
    __bf16* smPw = smP + w * (16 * 72);

    for (int kt = 0; kt < 16; ++kt) {
        const __bf16* Ks = Kg + (size_t)kt * 64 * DH;
        // stage K: 64 rows x 24 chunks; LDS linear dest, source chunk low3 ^= row&7
#pragma unroll
        for (int i = 0; i < 6; ++i) {
            int c = i * 256 + t;                 // 0..1535
            int row = c / 24, cc = c - row * 24;
            int scc = (cc & 0x18) | ((cc ^ row) & 7);
            gl2lds16(Ks + (size_t)row * DH + scc * 8,
                     (void*)(smK + (i * 256 + w * 64) * 8));
        }
        // stage V^T: 192 rows x 8 chunks; rows stride S in global
#pragma unroll
        for (int i = 0; i < 6; ++i) {
            int c = i * 256 + t;                 // 0..1535
            int row = c >> 3, cc = c & 7;
            int scc = cc ^ (row & 7);
            gl2lds16(VtG + (size_t)row * SS + kt * 64 + scc * 8,
                     (void*)(smVt + (i * 256 + w * 64) * 8));
        }
        __syncthreads();
        // S = Q K^T * scale  (16 q  x 64 keys per wave)
        f32x4 sc[4];
#pragma unroll
        for (int nt = 0; nt < 4; ++nt) sc[nt] = fz;
#pragma unroll
        for (int ks = 0; ks < 6; ++ks) {
#pragma unroll
            for (int nt = 0; nt < 4; ++nt) {
                int cc = ks * 4 + b4;
                int ccs = (cc & 0x18) | ((cc ^ r) & 7);   // row&7 == r&7
                bf16x8 kf = *(const bf16x8*)(smK + (nt * 16 + r) * 192 + ccs * 8);
                sc[nt] = MFMA_BF16(qf[ks], kf, sc[nt], 0, 0, 0);
            }
        }
#pragma unroll
        for (int nt = 0; nt < 4; ++nt) sc[nt] *= ATT_SCALE;
        // online softmax
        float alpha[4];
#pragma unroll
        for (int j = 0; j < 4; ++j) {
            float mx = fmaxf(fmaxf(sc[0][j], sc[1][j]), fmaxf(sc[2][j], sc[3][j]));
#pragma unroll
            for (int msk = 1; msk < 16; msk <<= 1) mx = fmaxf(mx, __shfl_xor(mx, msk));
            float mn = fmaxf(m_r[j], mx);
            alpha[j] = __expf(m_r[j] - mn);
            m_r[j] = mn;
            float p0 = __expf(sc[0][j] - mn);
            float p1 = __expf(sc[1][j] - mn);
            float p2 = __expf(sc[2][j] - mn);
            float p3 = __expf(sc[3][j] - mn);
            sc[0][j] = p0; sc[1][j] = p1; sc[2][j] = p2; sc[3][j] = p3;
            float ps = p0 + p1 + p2 + p3;
#pragma unroll
            for (int msk = 1; msk < 16; msk <<= 1) ps += __shfl_xor(ps, msk);
            l_r[j] = l_r[j] * alpha[j] + ps;
        }
        {
            f32x4 a4 = {alpha[0], alpha[1], alpha[2], alpha[3]};
#pragma unroll
            for (int i = 0; i < 12; ++i) oacc[i] *= a4;
        }
        // P -> per-wave LDS (bf16)
#pragma unroll
        for (int nt = 0; nt < 4; ++nt)
#pragma unroll
            for (int j = 0; j < 4; ++j)
                smPw[(b4 * 4 + j) * 72 + nt * 16 + r] = (__bf16)sc[nt][j];
        __asm__ volatile("s_waitcnt lgkmcnt(0)" ::: "memory");
        // O += P V
#pragma unroll
        for (int kt2 = 0; kt2 < 2; ++kt2) {
            bf16x8 pa = *(const bf16x8*)(smPw + r * 72 + kt2 * 32 + b4 * 8);
#pragma unroll
            for (int nt = 0; nt < 12; ++nt) {
                int ccs = (kt2 * 4 + b4) ^ (r & 7);        // row&7 == r&7
                bf16x8 vf = *(const bf16x8*)(smVt + (nt * 16 + r) * 64 + ccs * 8);
                oacc[nt] = MFMA_BF16(pa, vf, oacc[nt], 0, 0, 0);
            }
        }
        __syncthreads();
    }
    // write O / l  -> ao[b, s, h*D + d]
    float inv[4];
#pragma unroll
    for (int j = 0; j < 4; ++j) inv[j] = 1.0f / l_r[j];
    __bf16* obase = ao + (size_t)b * (SS * E);
#pragma unroll
    for (int nt = 0; nt < 12; ++nt)
#pragma unroll
        for (int j = 0; j < 4; ++j) {
            int srow = q0 + b4 * 4 + j;
            obase[(size_t)srow * E + h * DH + nt * 16 + r] = (__bf16)(oacc[nt][j] * inv[j]);
        }
}

// ---------------------------------------------------------------------------------
extern "C" void kernel_launch(void* const* d_in, const int* in_sizes, int n_in,
                              void* d_out, int out_size, void* d_ws, size_t ws_size,
                              hipStream_t stream) {
    const float* hs   = (const float*)d_in[0];
    const float* ln1s = (const float*)d_in[1];
    const float* ln1b = (const float*)d_in[2];
    const float* wq   = (const float*)d_in[3];
    const float* wk   = (const float*)d_in[4];
    const float* wv   = (const float*)d_in[5];
    const float* wo   = (const float*)d_in[6];
    const float* bo   = (const float*)d_in[7];
    const float* ln2s = (const float*)d_in[8];
    const float* ln2b = (const float*)d_in[9];
    const float* w1   = (const float*)d_in[10];
    const float* b1   = (const float*)d_in[11];
    const float* w2   = (const float*)d_in[12];
    const float* b2   = (const float*)d_in[13];
    float* X = (float*)d_out;

    char* ws = (char*)d_ws;
    size_t off = 0;
    auto alloc = [&](size_t bytes) {
        char* p = ws + off;
        off += (bytes + 255) & ~(size_t)255;
        return p;
    };
    __bf16* wq_b = (__bf16*)alloc((size_t)E * E * 2);
    __bf16* wk_b = (__bf16*)alloc((size_t)E * E * 2);
    __bf16* wv_b = (__bf16*)alloc((size_t)E * E * 2);
    __bf16* wo_b = (__bf16*)alloc((size_t)E * E * 2);
    __bf16* w1_b = (__bf16*)alloc((size_t)FF * E * 2);
    __bf16* w2_b = (__bf16*)alloc((size_t)FF * E * 2);
    __bf16* h_b  = (__bf16*)alloc((size_t)MM * E * 2);
    // U = 4 slots of MM*E bf16 (50.3 MB), also aliased whole by FFN intermediate
    char* U = alloc((size_t)MM * FF * 2);
    const size_t SLOT = (size_t)MM * E * 2;
    __bf16* q_b  = (__bf16*)U;                  // slot 0
    __bf16* k_b  = (__bf16*)(U + SLOT);         // slot 1
    __bf16* v_b  = (__bf16*)(U + 2 * SLOT);     // slot 2 (dead after vtrans)
    __bf16* vt_b = (__bf16*)(U + 3 * SLOT);     // slot 3: [bh*D + d][s]
    __bf16* a_b  = (__bf16*)(U + 2 * SLOT);     // slot 2 reused for attn out
    __bf16* f_b  = (__bf16*)U;

    // x lives in d_out (fp32); fresh copy every call keeps graph replays idempotent
    hipMemcpyAsync(d_out, hs, (size_t)MM * E * 4, hipMemcpyDeviceToDevice, stream);

    for (int i = 0; i < LAY; ++i) {
        Cast6 c;
        c.src[0] = wq + (size_t)i * E * E;  c.dst[0] = wq_b;
        c.src[1] = wk + (size_t)i * E * E;  c.dst[1] = wk_b;
        c.src[2] = wv + (size_t)i * E * E;  c.dst[2] = wv_b;
        c.src[3] = wo + (size_t)i * E * E;  c.dst[3] = wo_b;
        c.src[4] = w1 + (size_t)i * FF * E; c.dst[4] = w1_b;
        c.src[5] = w2 + (size_t)i * FF * E; c.dst[5] = w2_b;
        int n4[6] = {E * E / 4, E * E / 4, E * E / 4, E * E / 4, FF * E / 4, FF * E / 4};
        c.cum4[0] = 0;
        for (int k = 0; k < 6; ++k) c.cum4[k + 1] = c.cum4[k] + n4[k];
        int total4 = c.cum4[6];
        cast6_kernel<<<1024, 256, 0, stream>>>(c, total4);

        ln_kernel<<<MM, 256, 0, stream>>>(X, ln1s + (size_t)i * E, ln1b + (size_t)i * E, h_b);

        gemm128<0, 1><<<dim3(E / 128, MM / 128, 3), 256, 0, stream>>>(
            h_b, wq_b, wk_b, wv_b, q_b, k_b, v_b, nullptr, MM, E, E);

        vtrans_kernel<<<dim3(48, 32), 256, 0, stream>>>(v_b, vt_b);

        attn_kernel<<<dim3(SS / 64, HH, BB), 256, 0, stream>>>(q_b, k_b, vt_b, a_b);

        gemm128<2, 2><<<dim3(E / 128, MM / 128, 2), 256, 0, stream>>>(
            a_b, wo_b, wo_b, wo_b, X, X, X, bo + (size_t)i * E, MM, E, E);

        ln_kernel<<<MM, 256, 0, stream>>>(X, ln2s + (size_t)i * E, ln2b + (size_t)i * E, h_b);

        gemm128<1, 1><<<dim3(FF / 128, MM / 128, 1), 256, 0, stream>>>(
            h_b, w1_b, w1_b, w1_b, f_b, f_b, f_b, b1 + (size_t)i * FF, MM, FF, E);

        gemm128<2, 2><<<dim3(E / 128, MM / 128, 2), 256, 0, stream>>>(
            f_b, w2_b, w2_b, w2_b, X, X, X, b2 + (size_t)i * E, MM, E, FF);
    }
}